// Round 1
// baseline (1091.224 us; speedup 1.0000x reference)
//
#include <hip/hip_runtime.h>
#include <hip/hip_bf16.h>

// MultiHeadAttention B=2 H=16 S=2048 D=128, fp32 I/O, bf16 MFMA internal.
// Pipeline: prep(convert+zero) -> k_qkv (Q,K rowmajor + V transposed)
//        -> k_scores (QK^T, mask, exp -> weights area; rowsum atomics)
//        -> k_ctx (normalize weights in-place + PV GEMM -> concat)
//        -> k_out (concat @ Wd^T + bd -> out)

using short8 = __attribute__((ext_vector_type(8))) short;
using f32x4  = __attribute__((ext_vector_type(4))) float;

#define DEVFN static __device__ __forceinline__

DEVFN unsigned short f2bf(float f) {
    unsigned int u = __builtin_bit_cast(unsigned int, f);
    u += 0x7fffu + ((u >> 16) & 1u);   // RNE (no NaN inputs here)
    return (unsigned short)(u >> 16);
}
DEVFN float bf2f(unsigned short b) {
    unsigned int u = ((unsigned int)b) << 16;
    return __builtin_bit_cast(float, u);
}

// ---- stage ROWSx64 bf16 tile from global (row-major, ld elems) to LDS [ROWS][64]
template<int ROWS>
DEVFN void stage_bf16(const unsigned short* __restrict__ g, long ld,
                      unsigned short* lds, int tid) {
#pragma unroll
    for (int j = 0; j < ROWS / 32; ++j) {
        int c = tid + j * 256;
        int r = c >> 3, kc = (c & 7) << 3;
        *reinterpret_cast<uint4*>(lds + r * 64 + kc) =
            *reinterpret_cast<const uint4*>(g + (long)r * ld + kc);
    }
}

// ---- per-wave MFMA over one BK=64 K-tile. As: wave's MF*16 rows x 64k; Bs: NF*16 x 64k.
template<int MF, int NF>
DEVFN void mfma_tile(const unsigned short* As, const unsigned short* Bs,
                     f32x4 (&acc)[MF][NF], int lane) {
    int lr = lane & 15, lg = lane >> 4;
#pragma unroll
    for (int kk = 0; kk < 2; ++kk) {
        short8 a[MF], b[NF];
#pragma unroll
        for (int m = 0; m < MF; ++m)
            a[m] = *reinterpret_cast<const short8*>(As + (m * 16 + lr) * 64 + kk * 32 + lg * 8);
#pragma unroll
        for (int n = 0; n < NF; ++n)
            b[n] = *reinterpret_cast<const short8*>(Bs + (n * 16 + lr) * 64 + kk * 32 + lg * 8);
#pragma unroll
        for (int m = 0; m < MF; ++m)
#pragma unroll
            for (int n = 0; n < NF; ++n)
                acc[m][n] = __builtin_amdgcn_mfma_f32_16x16x32_bf16(a[m], b[n], acc[m][n], 0, 0, 0);
    }
}

// ---- prep: fp32->bf16 conversions + zero rowsum ------------------------------
__global__ __launch_bounds__(256) void k_prep(
        const float* __restrict__ x, const float* __restrict__ wq,
        const float* __restrict__ wk, const float* __restrict__ wv,
        const float* __restrict__ wd,
        unsigned short* __restrict__ xb, unsigned short* __restrict__ wqb,
        unsigned short* __restrict__ wkb, unsigned short* __restrict__ wvb,
        unsigned short* __restrict__ wdb, float* __restrict__ rowsum) {
    int i = blockIdx.x * 256 + threadIdx.x;
    if (i < 524288)        xb[i] = f2bf(x[i]);
    else if (i < 786432)   wqb[i - 524288]  = f2bf(wq[i - 524288]);
    else if (i < 1048576)  wkb[i - 786432]  = f2bf(wk[i - 786432]);
    else if (i < 1310720)  wvb[i - 1048576] = f2bf(wv[i - 1048576]);
    else if (i < 1572864)  wdb[i - 1310720] = f2bf(wd[i - 1310720]);
    else if (i < 1638400)  rowsum[i - 1572864] = 0.0f;
}

// ---- k_qkv: x(4096x128) @ W^T(2048x128 rowmajor) -> Q,K (B,H,S,D) / V^T (B,H,D,S)
__global__ __launch_bounds__(256) void k_qkv(
        const unsigned short* __restrict__ xb, const unsigned short* __restrict__ wqb,
        const unsigned short* __restrict__ wkb, const unsigned short* __restrict__ wvb,
        const float* __restrict__ bq, const float* __restrict__ bk,
        const float* __restrict__ bv,
        unsigned short* __restrict__ Qb, unsigned short* __restrict__ Kb,
        unsigned short* __restrict__ Vtb) {
    __shared__ __align__(16) char smem[32768];
    unsigned short* As = (unsigned short*)smem;
    unsigned short* Bs = (unsigned short*)(smem + 16384);
    unsigned short* Cs = (unsigned short*)smem;   // reused after barrier
    int tid = threadIdx.x, lane = tid & 63, wid = tid >> 6;
    int wr = wid >> 1, wc = wid & 1;
    int lr = lane & 15, lg = lane >> 4;
    int mt = blockIdx.x, nt = blockIdx.y, z = blockIdx.z;
    const unsigned short* Wb = (z == 0) ? wqb : ((z == 1) ? wkb : wvb);
    const float* bias = (z == 0) ? bq : ((z == 1) ? bk : bv);
    const unsigned short* gA = xb + (long)mt * 128 * 128;
    const unsigned short* gB = Wb + (long)nt * 128 * 128;
    f32x4 acc[4][4] = {};
#pragma unroll
    for (int kt = 0; kt < 2; ++kt) {
        __syncthreads();
        stage_bf16<128>(gA + kt * 64, 128, As, tid);
        stage_bf16<128>(gB + kt * 64, 128, Bs, tid);
        __syncthreads();
        mfma_tile<4, 4>(As + wr * 64 * 64, Bs + wc * 64 * 64, acc, lane);
    }
    __syncthreads();
#pragma unroll
    for (int n = 0; n < 4; ++n) {
        int col = wc * 64 + n * 16 + lr;
        float bval = bias[nt * 128 + col];
#pragma unroll
        for (int m = 0; m < 4; ++m)
#pragma unroll
            for (int r = 0; r < 4; ++r) {
                int row = wr * 64 + m * 16 + lg * 4 + r;
                Cs[row * 128 + col] = f2bf(acc[m][n][r] + bval);
            }
    }
    __syncthreads();
    int rg0 = mt * 128;
    int b = rg0 >> 11, s0 = rg0 & 2047, h = nt;   // BN=128 == D, so nt == head
    if (z < 2) {
        unsigned short* dst = ((z == 0) ? Qb : Kb) + ((long)(b * 16 + h) * 2048 + s0) * 128;
#pragma unroll
        for (int j = 0; j < 8; ++j) {
            int c = tid + j * 256;
            int r = c >> 4, cc2 = (c & 15) << 3;
            *reinterpret_cast<uint4*>(dst + (long)r * 128 + cc2) =
                *reinterpret_cast<uint4*>(Cs + r * 128 + cc2);
        }
    } else {
        unsigned short* dst = Vtb + (long)(b * 16 + h) * 128 * 2048;
#pragma unroll
        for (int j = 0; j < 8; ++j) {
            int c = tid + j * 256;
            int d = c >> 4, sl = (c & 15) << 3;
            unsigned int w0 = (unsigned int)Cs[(sl + 0) * 128 + d] | ((unsigned int)Cs[(sl + 1) * 128 + d] << 16);
            unsigned int w1 = (unsigned int)Cs[(sl + 2) * 128 + d] | ((unsigned int)Cs[(sl + 3) * 128 + d] << 16);
            unsigned int w2 = (unsigned int)Cs[(sl + 4) * 128 + d] | ((unsigned int)Cs[(sl + 5) * 128 + d] << 16);
            unsigned int w3 = (unsigned int)Cs[(sl + 6) * 128 + d] | ((unsigned int)Cs[(sl + 7) * 128 + d] << 16);
            *reinterpret_cast<uint4*>(dst + (long)d * 2048 + s0 + sl) = make_uint4(w0, w1, w2, w3);
        }
    }
}

// ---- k_scores: exp((Q K^T)*scale + mask) -> weights area (fp32) + rowsum atomics
__global__ __launch_bounds__(256) void k_scores(
        const unsigned short* __restrict__ Qb, const unsigned short* __restrict__ Kb,
        const int* __restrict__ mask, float* __restrict__ wout,
        float* __restrict__ rowsum) {
    __shared__ __align__(16) char smem[32768];
    unsigned short* As = (unsigned short*)smem;
    unsigned short* Bs = (unsigned short*)(smem + 16384);
    unsigned short* Cs = (unsigned short*)smem;
    int tid = threadIdx.x, lane = tid & 63, wid = tid >> 6;
    int wr = wid >> 1, wc = wid & 1;
    int lr = lane & 15, lg = lane >> 4;
    int z = blockIdx.z, b = z >> 4;
    int s0 = blockIdx.x * 128, t0 = blockIdx.y * 128;
    const unsigned short* gA = Qb + (long)z * 2048 * 128 + (long)s0 * 128;
    const unsigned short* gB = Kb + (long)z * 2048 * 128 + (long)t0 * 128;
    f32x4 acc[4][4] = {};
#pragma unroll
    for (int kt = 0; kt < 2; ++kt) {
        __syncthreads();
        stage_bf16<128>(gA + kt * 64, 128, As, tid);
        stage_bf16<128>(gB + kt * 64, 128, Bs, tid);
        __syncthreads();
        mfma_tile<4, 4>(As + wr * 64 * 64, Bs + wc * 64 * 64, acc, lane);
    }
    __syncthreads();
    const float SCALE = 0.08838834764831845f;   // 1/sqrt(128)
    const int* gM = mask + (long)b * 2048 * 2048;
    // mask + exp (unmasked scores ~N(0,0.05): plain exp is numerically safe)
#pragma unroll
    for (int m = 0; m < 4; ++m)
#pragma unroll
        for (int n = 0; n < 4; ++n)
#pragma unroll
            for (int r = 0; r < 4; ++r) {
                int row = wr * 64 + m * 16 + lg * 4 + r;
                int col = wc * 64 + n * 16 + lr;
                int mk = gM[(long)(s0 + row) * 2048 + t0 + col];
                acc[m][n][r] = mk ? 0.0f : __expf(acc[m][n][r] * SCALE);
            }
    // partial row sums: reduce over this wave's 64 cols, one atomic per row per wave
    float* rsz = rowsum + z * 2048 + s0;
#pragma unroll
    for (int m = 0; m < 4; ++m)
#pragma unroll
        for (int r = 0; r < 4; ++r) {
            float sv = acc[m][0][r] + acc[m][1][r] + acc[m][2][r] + acc[m][3][r];
            sv += __shfl_xor(sv, 1);
            sv += __shfl_xor(sv, 2);
            sv += __shfl_xor(sv, 4);
            sv += __shfl_xor(sv, 8);
            if (lr == 0) {
                int row = wr * 64 + m * 16 + lg * 4 + r;
                atomicAdd(rsz + row, sv);
            }
        }
    // restage (bf16) for coalesced fp32 write of exp values
#pragma unroll
    for (int m = 0; m < 4; ++m)
#pragma unroll
        for (int n = 0; n < 4; ++n)
#pragma unroll
            for (int r = 0; r < 4; ++r) {
                int row = wr * 64 + m * 16 + lg * 4 + r;
                int col = wc * 64 + n * 16 + lr;
                Cs[row * 128 + col] = f2bf(acc[m][n][r]);
            }
    __syncthreads();
    float* dst = wout + (long)z * 2048 * 2048 + (long)s0 * 2048 + t0;
#pragma unroll
    for (int j = 0; j < 8; ++j) {
        int c = tid + j * 256;
        int r = c >> 4, cc2 = (c & 15) << 3;
        uint4 uv = *reinterpret_cast<uint4*>(Cs + r * 128 + cc2);
        float4 lo, hi;
        lo.x = bf2f((unsigned short)(uv.x & 0xffff)); lo.y = bf2f((unsigned short)(uv.x >> 16));
        lo.z = bf2f((unsigned short)(uv.y & 0xffff)); lo.w = bf2f((unsigned short)(uv.y >> 16));
        hi.x = bf2f((unsigned short)(uv.z & 0xffff)); hi.y = bf2f((unsigned short)(uv.z >> 16));
        hi.z = bf2f((unsigned short)(uv.w & 0xffff)); hi.w = bf2f((unsigned short)(uv.w >> 16));
        *reinterpret_cast<float4*>(dst + (long)r * 2048 + cc2) = lo;
        *reinterpret_cast<float4*>(dst + (long)r * 2048 + cc2 + 4) = hi;
    }
}

// ---- k_ctx: normalize weights in-place + ctx = P @ V -> concat (B,S,H*D) bf16
__global__ __launch_bounds__(256) void k_ctx(
        float* __restrict__ wio, const float* __restrict__ rowsum,
        const unsigned short* __restrict__ Vtb, unsigned short* __restrict__ ccb) {
    __shared__ __align__(16) char smem[32768];
    unsigned short* As = (unsigned short*)smem;
    unsigned short* Bs = (unsigned short*)(smem + 16384);
    unsigned short* Cs = (unsigned short*)smem;
    int tid = threadIdx.x, lane = tid & 63, wid = tid >> 6;
    int wr = wid >> 1, wc = wid & 1;
    int lr = lane & 15, lg = lane >> 4;
    int z = blockIdx.z, b = z >> 4, h = z & 15;
    int s0 = blockIdx.x * 128;
    float* gW = wio + (long)z * 2048 * 2048 + (long)s0 * 2048;
    const unsigned short* gV = Vtb + (long)z * 128 * 2048;
    const float* rs = rowsum + z * 2048 + s0;
    f32x4 acc[4][4] = {};
    for (int kt = 0; kt < 32; ++kt) {
        __syncthreads();
        // A-stage: read exp fp32, normalize, write back (final weights), bf16 to LDS
#pragma unroll
        for (int j = 0; j < 8; ++j) {
            int c = tid + j * 256;
            int r = c >> 4, kc = (c & 15) << 2;
            long off = (long)r * 2048 + kt * 64 + kc;
            float4 w = *reinterpret_cast<float4*>(gW + off);
            float inv = 1.0f / rs[r];
            w.x *= inv; w.y *= inv; w.z *= inv; w.w *= inv;
            *reinterpret_cast<float4*>(gW + off) = w;
            unsigned int p0 = (unsigned int)f2bf(w.x) | ((unsigned int)f2bf(w.y) << 16);
            unsigned int p1 = (unsigned int)f2bf(w.z) | ((unsigned int)f2bf(w.w) << 16);
            *reinterpret_cast<uint2*>(As + r * 64 + kc) = make_uint2(p0, p1);
        }
        stage_bf16<128>(gV + kt * 64, 2048, Bs, tid);
        __syncthreads();
        mfma_tile<4, 4>(As + wr * 64 * 64, Bs + wc * 64 * 64, acc, lane);
    }
    __syncthreads();
#pragma unroll
    for (int m = 0; m < 4; ++m)
#pragma unroll
        for (int n = 0; n < 4; ++n)
#pragma unroll
            for (int r = 0; r < 4; ++r) {
                int row = wr * 64 + m * 16 + lg * 4 + r;
                int col = wc * 64 + n * 16 + lr;
                Cs[row * 128 + col] = f2bf(acc[m][n][r]);
            }
    __syncthreads();
    unsigned short* dst = ccb + ((long)b * 2048 + s0) * 2048 + h * 128;
#pragma unroll
    for (int j = 0; j < 8; ++j) {
        int c = tid + j * 256;
        int r = c >> 4, cc2 = (c & 15) << 3;
        *reinterpret_cast<uint4*>(dst + (long)r * 2048 + cc2) =
            *reinterpret_cast<uint4*>(Cs + r * 128 + cc2);
    }
}

// ---- k_out: concat(4096x2048) @ Wd^T(128x2048) + bd -> out fp32 (BM=64 for occupancy)
__global__ __launch_bounds__(256) void k_out(
        const unsigned short* __restrict__ ccb, const unsigned short* __restrict__ wdb,
        const float* __restrict__ bd, float* __restrict__ out) {
    __shared__ __align__(16) char smem[24576];
    unsigned short* As = (unsigned short*)smem;            // 64x64x2 = 8K
    unsigned short* Bs = (unsigned short*)(smem + 8192);   // 128x64x2 = 16K
    unsigned short* Cs = (unsigned short*)smem;            // 64x128x2 = 16K (reuse)
    int tid = threadIdx.x, lane = tid & 63, wid = tid >> 6;
    int wr = wid >> 1, wc = wid & 1;
    int lr = lane & 15, lg = lane >> 4;
    int mt = blockIdx.x;
    const unsigned short* gA = ccb + (long)mt * 64 * 2048;
    f32x4 acc[2][4] = {};
    for (int kt = 0; kt < 32; ++kt) {
        __syncthreads();
        stage_bf16<64>(gA + kt * 64, 2048, As, tid);
        stage_bf16<128>(wdb + kt * 64, 2048, Bs, tid);
        __syncthreads();
        mfma_tile<2, 4>(As + wr * 32 * 64, Bs + wc * 64 * 64, acc, lane);
    }
    __syncthreads();
#pragma unroll
    for (int n = 0; n < 4; ++n) {
        int col = wc * 64 + n * 16 + lr;
        float bval = bd[col];
#pragma unroll
        for (int m = 0; m < 2; ++m)
#pragma unroll
            for (int r = 0; r < 4; ++r) {
                int row = wr * 32 + m * 16 + lg * 4 + r;
                Cs[row * 128 + col] = f2bf(acc[m][n][r] + bval);
            }
    }
    __syncthreads();
    float* dst = out + (long)mt * 64 * 128;
#pragma unroll
    for (int j = 0; j < 8; ++j) {
        int c = tid + j * 256;
        int r = c >> 5, cc2 = (c & 31) << 2;
        uint2 uv = *reinterpret_cast<uint2*>(Cs + r * 128 + cc2);
        float4 o;
        o.x = bf2f((unsigned short)(uv.x & 0xffff));
        o.y = bf2f((unsigned short)(uv.x >> 16));
        o.z = bf2f((unsigned short)(uv.y & 0xffff));
        o.w = bf2f((unsigned short)(uv.y >> 16));
        *reinterpret_cast<float4*>(dst + r * 128 + cc2) = o;
    }
}

extern "C" void kernel_launch(void* const* d_in, const int* in_sizes, int n_in,
                              void* d_out, int out_size, void* d_ws, size_t ws_size,
                              hipStream_t stream) {
    const float* x  = (const float*)d_in[0];
    const int* mask = (const int*)d_in[1];
    const float* Wq = (const float*)d_in[2];
    const float* bq = (const float*)d_in[3];
    const float* Wk = (const float*)d_in[4];
    const float* bk = (const float*)d_in[5];
    const float* Wv = (const float*)d_in[6];
    const float* bv = (const float*)d_in[7];
    const float* Wd = (const float*)d_in[8];
    const float* bd = (const float*)d_in[9];

    float* out  = (float*)d_out;
    float* wout = out + 524288;   // weights (B,H,S,S) fp32 after out (B,S,D)

    char* ws = (char*)d_ws;       // ~70.5 MB used
    unsigned short* xb   = (unsigned short*)(ws + 0);
    unsigned short* wqb  = (unsigned short*)(ws + 1048576);
    unsigned short* wkb  = (unsigned short*)(ws + 1572864);
    unsigned short* wvb  = (unsigned short*)(ws + 2097152);
    unsigned short* wdb  = (unsigned short*)(ws + 2621440);
    unsigned short* Qb   = (unsigned short*)(ws + 3145728);
    unsigned short* Kb   = (unsigned short*)(ws + 19922944);
    unsigned short* Vtb  = (unsigned short*)(ws + 36700160);
    unsigned short* ccb  = (unsigned short*)(ws + 53477376);
    float*          rsum = (float*)(ws + 70254592);

    k_prep<<<6400, 256, 0, stream>>>(x, Wq, Wk, Wv, Wd, xb, wqb, wkb, wvb, wdb, rsum);
    k_qkv<<<dim3(32, 16, 3), 256, 0, stream>>>(xb, wqb, wkb, wvb, bq, bk, bv, Qb, Kb, Vtb);
    k_scores<<<dim3(16, 16, 32), 256, 0, stream>>>(Qb, Kb, mask, wout, rsum);
    k_ctx<<<dim3(16, 1, 32), 256, 0, stream>>>(wout, rsum, Vtb, ccb);
    k_out<<<dim3(64, 1, 1), 256, 0, stream>>>(ccb, wdb, bd, out);
}